// Round 8
// baseline (1962.154 us; speedup 1.0000x reference)
//
#include <hip/hip_runtime.h>
#include <hip/hip_bf16.h>

#define DD 128
#define CAP 48

typedef __attribute__((ext_vector_type(8))) short bf16x8;
typedef __attribute__((ext_vector_type(4))) float f32x4;

// split 8 fp32 -> packed bf16 hi (truncate) and lo (truncate of residual)
__device__ __forceinline__ void cvt8(const float4 a0, const float4 a1,
                                     bf16x8& hi, bf16x8& lo)
{
    float af[8] = {a0.x, a0.y, a0.z, a0.w, a1.x, a1.y, a1.z, a1.w};
    union { unsigned int u[4]; bf16x8 v; } H, L;
    #pragma unroll
    for (int i = 0; i < 4; ++i) {
        unsigned int b0 = __float_as_uint(af[2*i]);
        unsigned int b1 = __float_as_uint(af[2*i+1]);
        unsigned int h0 = b0 & 0xFFFF0000u;
        unsigned int h1 = b1 & 0xFFFF0000u;
        H.u[i] = (h0 >> 16) | h1;
        float r0 = af[2*i]   - __uint_as_float(h0);
        float r1 = af[2*i+1] - __uint_as_float(h1);
        L.u[i] = (__float_as_uint(r0) >> 16) | (__float_as_uint(r1) & 0xFFFF0000u);
    }
    hi = H.v; lo = L.v;
}

// Y[n][cb*128+...] = act( X[n][:] @ Wunit[cb] + bias[cb*128+...] ), linear stores
__global__ __launch_bounds__(256) void gemm_mfma(
    const float* __restrict__ X, const unsigned short* __restrict__ Wt,
    const float* __restrict__ bias, float* __restrict__ Y,
    int N, int ldY, int act)
{
    const int lane = threadIdx.x & 63;
    const int wid  = threadIdx.x >> 6;
    const int wr = wid >> 1, wc = wid & 1;
    const int row0 = blockIdx.x * 128 + wr * 64;
    const int cb   = blockIdx.y;
    const unsigned short* WtH = Wt + (size_t)cb * 32768;
    const unsigned short* WtL = WtH + 16384;

    const int l15 = lane & 15;
    const int kg  = (lane >> 4) * 8;

    f32x4 acc[4][4] = {};

    int arow[4];
    #pragma unroll
    for (int mi = 0; mi < 4; ++mi) {
        int r = row0 + mi * 16 + l15;
        arow[mi] = r < N ? r : N - 1;
    }

    #pragma unroll
    for (int kc = 0; kc < 4; ++kc) {
        const int kb = kc * 32 + kg;
        bf16x8 ah[4], al[4], bh[4], bl[4];
        #pragma unroll
        for (int mi = 0; mi < 4; ++mi) {
            const float* p = X + (size_t)arow[mi] * DD + kb;
            float4 a0 = *(const float4*)p;
            float4 a1 = *(const float4*)(p + 4);
            cvt8(a0, a1, ah[mi], al[mi]);
        }
        #pragma unroll
        for (int ni = 0; ni < 4; ++ni) {
            int m = wc * 64 + ni * 16 + l15;
            bh[ni] = *(const bf16x8*)(WtH + (size_t)m * DD + kb);
            bl[ni] = *(const bf16x8*)(WtL + (size_t)m * DD + kb);
        }
        #pragma unroll
        for (int mi = 0; mi < 4; ++mi)
            #pragma unroll
            for (int ni = 0; ni < 4; ++ni) {
                acc[mi][ni] = __builtin_amdgcn_mfma_f32_16x16x32_bf16(ah[mi], bh[ni], acc[mi][ni], 0, 0, 0);
                acc[mi][ni] = __builtin_amdgcn_mfma_f32_16x16x32_bf16(ah[mi], bl[ni], acc[mi][ni], 0, 0, 0);
                acc[mi][ni] = __builtin_amdgcn_mfma_f32_16x16x32_bf16(al[mi], bh[ni], acc[mi][ni], 0, 0, 0);
            }
    }

    const int colW = cb * 128 + wc * 64;
    #pragma unroll
    for (int ni = 0; ni < 4; ++ni) {
        float bv = bias[colW + ni * 16 + l15];
        #pragma unroll
        for (int mi = 0; mi < 4; ++mi) {
            #pragma unroll
            for (int r = 0; r < 4; ++r) {
                int row = row0 + mi * 16 + (lane >> 4) * 4 + r;
                if (row < N) {
                    float v = acc[mi][ni][r] + bv;
                    Y[(size_t)row * ldY + colW + ni * 16 + l15] = act ? fmaxf(v, 0.f) : v;
                }
            }
        }
    }
}

// one-time: transpose+split weight units to bf16 hi/lo [m][k].
__global__ __launch_bounds__(256) void prep_weights(
    const float* __restrict__ embW, const float* __restrict__ keyW,
    const float* __restrict__ qryW, const float* __restrict__ valW,
    const float* __restrict__ skpW, const float* __restrict__ g1W,
    const float* __restrict__ g2W, const float* __restrict__ h1W,
    const float* __restrict__ h2W,
    const float* __restrict__ keyb, const float* __restrict__ qryb,
    const float* __restrict__ valb, const float* __restrict__ skpb,
    unsigned short* __restrict__ Wt, float* __restrict__ biasCat)
{
    const int u = blockIdx.x;   // 0..14
    const int t = threadIdx.x;
    __shared__ float T[128][129];

    const float* src;
    if (u < 3)       src = embW + (size_t)u * 16384;
    else if (u < 7)  { const float* p[4] = {keyW, qryW, valW, skpW}; src = p[u - 3]; }
    else if (u < 11) { const float* p[4] = {keyW, qryW, valW, skpW}; src = p[u - 7] + 16384; }
    else if (u == 11) src = g1W;
    else if (u == 12) src = g2W;
    else if (u == 13) src = h1W;
    else              src = h2W;

    #pragma unroll
    for (int i = 0; i < 64; ++i) {
        int idx = t + 256 * i;
        T[idx >> 7][idx & 127] = src[idx];
    }
    __syncthreads();

    unsigned short* dH = Wt + (size_t)u * 32768;
    unsigned short* dL = dH + 16384;
    const int m = t >> 1, kbase = (t & 1) * 64;
    for (int j = 0; j < 64; ++j) {
        int k = kbase + j;
        float a = T[k][m];
        unsigned int b = __float_as_uint(a);
        unsigned int h = b & 0xFFFF0000u;
        float r = a - __uint_as_float(h);
        dH[m * 128 + k] = (unsigned short)(h >> 16);
        dL[m * 128 + k] = (unsigned short)(__float_as_uint(r) >> 16);
    }

    if (u == 0) {
        for (int x = t; x < 1024; x += 256) {
            int L = x >> 9, c = x & 511;
            const float* bp = (c < 128) ? keyb : (c < 256) ? qryb : (c < 384) ? valb : skpb;
            biasCat[x] = bp[L * 128 + (c & 127)];
        }
    }
}

// ---------------- CSR build ----------------
__global__ void hist_kernel(const int* __restrict__ dstA, int* __restrict__ hist, int E)
{
    for (int e = blockIdx.x * blockDim.x + threadIdx.x; e < E;
         e += gridDim.x * blockDim.x)
        atomicAdd(&hist[dstA[e]], 1);
}

__global__ __launch_bounds__(256) void scan1_kernel(
    const int* __restrict__ in, int n_in,
    int* __restrict__ out, int* __restrict__ bsum, int n)
{
    __shared__ int wtot[4];
    const int t = threadIdx.x, lane = t & 63, wv = t >> 6;
    const int base = blockIdx.x * 1024 + t * 4;
    int v[4]; int sum = 0;
    #pragma unroll
    for (int j = 0; j < 4; ++j) {
        int idx = base + j;
        v[j] = (idx < n_in) ? in[idx] : 0;
        sum += v[j];
    }
    int incl = sum;
    #pragma unroll
    for (int d = 1; d < 64; d <<= 1) {
        int y = __shfl_up(incl, d, 64);
        if (lane >= d) incl += y;
    }
    if (lane == 63) wtot[wv] = incl;
    __syncthreads();
    int woff = 0;
    for (int w = 0; w < wv; ++w) woff += wtot[w];
    int run = woff + incl - sum;
    #pragma unroll
    for (int j = 0; j < 4; ++j) {
        int idx = base + j;
        if (idx < n) out[idx] = run;
        run += v[j];
    }
    if (t == 0)
        bsum[blockIdx.x] = wtot[0] + wtot[1] + wtot[2] + wtot[3];
}

__global__ void scan2_kernel(int* __restrict__ bsum, int nb)
{
    if (blockIdx.x == 0 && threadIdx.x == 0) {
        int run = 0;
        for (int i = 0; i < nb; ++i) { int t = bsum[i]; bsum[i] = run; run += t; }
    }
}

__global__ __launch_bounds__(256) void scan3_kernel(
    int* __restrict__ out, const int* __restrict__ bsum,
    int* __restrict__ cursor, int n, int n_nodes)
{
    const int base = blockIdx.x * 1024 + threadIdx.x * 4;
    const int add = bsum[blockIdx.x];
    #pragma unroll
    for (int j = 0; j < 4; ++j) {
        int idx = base + j;
        if (idx < n) {
            int vv = out[idx] + add;
            out[idx] = vv;
            if (idx < n_nodes) cursor[idx] = vv;
        }
    }
}

__global__ void scatter_kernel(const int* __restrict__ srcA, const int* __restrict__ dstA,
                               int* __restrict__ cursor, int* __restrict__ perm,
                               int* __restrict__ srcp, int E)
{
    for (int e = blockIdx.x * blockDim.x + threadIdx.x; e < E;
         e += gridDim.x * blockDim.x) {
        int d = dstA[e];
        int pos = atomicAdd(&cursor[d], 1);
        perm[pos] = e;
        srcp[pos] = srcA[e];
    }
}

// ---------------- edge aggregation: LDS bulk staging, 4 dsts / block ----------------
// fused layout per row: [K | Q | V | Sk] (4 x 128)
__global__ __launch_bounds__(256) void edge_agg7(
    const int* __restrict__ row_ptr, const int* __restrict__ srcp,
    const float* __restrict__ ea, const int* __restrict__ perm,
    const float* __restrict__ We, const float* __restrict__ be,
    const float* __restrict__ fused, float* __restrict__ X, int N)
{
    __shared__ float qvLds[CAP][256];   // [slot][ q0..q127 | v0..v127 ]
    __shared__ float eaLds[CAP][24];    // padded to 24 for float4 reads
    __shared__ int   srcLds[CAP];
    __shared__ int   rowLds[5];

    const int tid = threadIdx.x;
    const int wv = tid >> 6, lane = tid & 63;
    const int d0 = blockIdx.x * 4;

    if (tid < 5) {
        int dd = d0 + tid;
        rowLds[tid] = row_ptr[dd <= N ? dd : N];
    }
    __syncthreads();

    const int I0  = rowLds[0];
    const int cnt = rowLds[4] - I0;
    const int stg = cnt < CAP ? cnt : CAP;

    if (tid < stg) srcLds[tid] = srcp[I0 + tid];
    __syncthreads();

    // ---- phase A: bulk-parallel staging (no dependent chains) ----
    {
        const int nw = (stg - wv + 3) >> 2;
        #pragma unroll 4
        for (int k = 0; k < nw; ++k) {
            const int s = wv + 4 * k;
            const int src = srcLds[s];
            const float4 t = *(const float4*)(fused + (size_t)src * 512 + 128 + lane * 4);
            *(float4*)&qvLds[s][lane * 4] = t;
        }
    }
    {
        const int tot = stg * 21;
        #pragma unroll 4
        for (int x = tid; x < tot; x += 256) {
            const int e = x / 21, j = x - e * 21;
            eaLds[e][j] = ea[(size_t)perm[I0 + e] * 21 + j];
        }
    }
    __syncthreads();

    // ---- phase B: per-wave aggregation, LDS-only inner loop ----
    const int d = d0 + wv;
    if (d >= N) return;
    const int c = lane * 2;

    float2 w[21];
    #pragma unroll
    for (int j = 0; j < 21; ++j)
        w[j] = *(const float2*)(We + j * DD + c);
    const float2 b2 = *(const float2*)(be + c);
    const float* fd = fused + (size_t)d * 512;
    const float2 kd = *(const float2*)(fd + c);
    const float2 sk = *(const float2*)(fd + 384 + c);

    float ax = 0.f, ay = 0.f;
    const int i0 = rowLds[wv], i1 = rowLds[wv + 1];
    const int capEnd = I0 + CAP;
    const int iS = i1 < capEnd ? i1 : capEnd;   // staged portion end

    for (int i = i0; i < iS; ++i) {
        const int s = i - I0;
        float4 e0 = *(const float4*)&eaLds[s][0];
        float4 e1 = *(const float4*)&eaLds[s][4];
        float4 e2 = *(const float4*)&eaLds[s][8];
        float4 e3 = *(const float4*)&eaLds[s][12];
        float4 e4 = *(const float4*)&eaLds[s][16];
        float  e5 = eaLds[s][20];
        float2 q = *(const float2*)&qvLds[s][c];
        float2 v = *(const float2*)&qvLds[s][128 + c];

        float aA[21] = {e0.x,e0.y,e0.z,e0.w, e1.x,e1.y,e1.z,e1.w,
                        e2.x,e2.y,e2.z,e2.w, e3.x,e3.y,e3.z,e3.w,
                        e4.x,e4.y,e4.z,e4.w, e5};
        float px[4] = {0,0,0,0}, py[4] = {0,0,0,0};
        #pragma unroll
        for (int j = 0; j < 21; ++j) {
            int ss = j & 3;
            px[ss] = fmaf(aA[j], w[j].x, px[ss]);
            py[ss] = fmaf(aA[j], w[j].y, py[ss]);
        }
        float zx = kd.x + q.x + (px[0] + px[1]) + (px[2] + px[3]) + b2.x;
        float zy = kd.y + q.y + (py[0] + py[1]) + (py[2] + py[3]) + b2.y;
        float gx = 1.f / (1.f + __expf(-zx));
        float gy = 1.f / (1.f + __expf(-zy));
        ax = fmaf(gx, v.x, ax);
        ay = fmaf(gy, v.y, ay);
    }

    // overflow tail (rare): direct global path
    for (int i = (i0 > iS ? i0 : iS); i < i1; ++i) {
        const float* eap = ea + (size_t)perm[i] * 21;
        const int s = srcp[i];
        const float* fp = fused + (size_t)s * 512;
        float2 q = *(const float2*)(fp + 128 + c);
        float2 v = *(const float2*)(fp + 256 + c);
        float4 A0 = *(const float4*)(eap);
        float4 A1 = *(const float4*)(eap + 4);
        float4 A2 = *(const float4*)(eap + 8);
        float4 A3 = *(const float4*)(eap + 12);
        float4 A4 = *(const float4*)(eap + 16);
        float  A5 = eap[20];
        float aA[21] = {A0.x,A0.y,A0.z,A0.w, A1.x,A1.y,A1.z,A1.w,
                        A2.x,A2.y,A2.z,A2.w, A3.x,A3.y,A3.z,A3.w,
                        A4.x,A4.y,A4.z,A4.w, A5};
        float px[4] = {0,0,0,0}, py[4] = {0,0,0,0};
        #pragma unroll
        for (int j = 0; j < 21; ++j) {
            int ss = j & 3;
            px[ss] = fmaf(aA[j], w[j].x, px[ss]);
            py[ss] = fmaf(aA[j], w[j].y, py[ss]);
        }
        float zx = kd.x + q.x + (px[0] + px[1]) + (px[2] + px[3]) + b2.x;
        float zy = kd.y + q.y + (py[0] + py[1]) + (py[2] + py[3]) + b2.y;
        float gx = 1.f / (1.f + __expf(-zx));
        float gy = 1.f / (1.f + __expf(-zy));
        ax = fmaf(gx, v.x, ax);
        ay = fmaf(gy, v.y, ay);
    }

    X[(size_t)d * DD + c]     = fmaxf(ax + sk.x, 0.f);
    X[(size_t)d * DD + c + 1] = fmaxf(ay + sk.y, 0.f);
}

// column sums of x[N][128] into gsum[128] (gsum pre-zeroed)
__global__ void colsum_kernel(const float* __restrict__ x, float* __restrict__ gsum, int N)
{
    const int c = threadIdx.x;
    float acc = 0.f;
    for (int r = blockIdx.x; r < N; r += gridDim.x)
        acc += x[(size_t)r * DD + c];
    atomicAdd(&gsum[c], acc);
}

__global__ void cvec_kernel(const float* __restrict__ gsum, const float* __restrict__ h1W,
                            const float* __restrict__ h1b, float* __restrict__ cvec, float invN)
{
    const int m = threadIdx.x;
    float acc = h1b[m];
    for (int k = 0; k < 128; ++k)
        acc = fmaf(gsum[k] * invN, h1W[(size_t)(128 + k) * DD + m], acc);
    cvec[m] = acc;
}

__global__ __launch_bounds__(256) void head3_kernel(
    const float* __restrict__ x, const float* __restrict__ w,
    const float* __restrict__ b, float* __restrict__ out, int N)
{
    const int wave = threadIdx.x >> 6;
    const int lane = threadIdx.x & 63;
    const long n = (long)blockIdx.x * 4 + wave;
    if (n >= N) return;
    float acc = x[n * DD + lane] * w[lane] + x[n * DD + 64 + lane] * w[64 + lane];
    #pragma unroll
    for (int off = 32; off > 0; off >>= 1)
        acc += __shfl_down(acc, off, 64);
    if (lane == 0) out[n] = acc + b[0];
}

extern "C" void kernel_launch(void* const* d_in, const int* in_sizes, int n_in,
                              void* d_out, int out_size, void* d_ws, size_t ws_size,
                              hipStream_t stream)
{
    const float* G    = (const float*)d_in[0];
    const int*   ei   = (const int*)  d_in[1];
    const float* ea   = (const float*)d_in[2];
    const float* embW = (const float*)d_in[3];
    const float* embb = (const float*)d_in[4];
    const float* keyW = (const float*)d_in[5];
    const float* keyb = (const float*)d_in[6];
    const float* qryW = (const float*)d_in[7];
    const float* qryb = (const float*)d_in[8];
    const float* valW = (const float*)d_in[9];
    const float* valb = (const float*)d_in[10];
    const float* skpW = (const float*)d_in[11];
    const float* skpb = (const float*)d_in[12];
    const float* edgW = (const float*)d_in[13];
    const float* edgb = (const float*)d_in[14];
    const float* g1W  = (const float*)d_in[15];
    const float* g1b  = (const float*)d_in[16];
    const float* g2W  = (const float*)d_in[17];
    const float* g2b  = (const float*)d_in[18];
    const float* h1W  = (const float*)d_in[19];
    const float* h1b  = (const float*)d_in[20];
    const float* h2W  = (const float*)d_in[21];
    const float* h2b  = (const float*)d_in[22];
    const float* h3W  = (const float*)d_in[23];
    const float* h3b  = (const float*)d_in[24];

    const int N = in_sizes[0] / DD;    // 100000
    const int E = in_sizes[2] / 21;    // 1000000
    const int* srcA = ei;
    const int* dstA = ei + E;

    const size_t S = (size_t)N * DD;
    float* bx     = (float*)d_ws;      // [N][128]
    float* b2     = bx + S;            // [N][128]
    float* bfused = b2 + S;            // [N][512]  (K | Q | V | Sk)
    float* gsum   = bfused + (size_t)N * 512;   // 128
    float* cvec   = gsum + DD;         // 128
    float* biasCat= cvec + DD;         // 1024
    unsigned short* Wt = (unsigned short*)(biasCat + 1024);  // 15*32768 ushorts
    int* hist = (int*)((char*)Wt + (size_t)15 * 32768 * 2);  // N
    int* row  = hist + N;              // N+1
    int* cur  = row + N + 1;           // N
    int* bsum = cur + N;               // 128
    int* perm = bsum + 128;            // E
    int* srcp = perm + E;              // E

    const dim3 g1grid((N + 127) / 128, 1);
    const dim3 g4grid((N + 127) / 128, 4);
    const int aggGrid = (N + 3) / 4;
    const int waveGrid = (N + 3) / 4;
    const int nScan = N + 1;
    const int nb = (nScan + 1023) / 1024;

    // ---- weight prep + CSR build ----
    prep_weights<<<15, 256, 0, stream>>>(embW, keyW, qryW, valW, skpW,
                                         g1W, g2W, h1W, h2W,
                                         keyb, qryb, valb, skpb, Wt, biasCat);
    hipMemsetAsync(hist, 0, (size_t)N * sizeof(int), stream);
    hist_kernel<<<1024, 256, 0, stream>>>(dstA, hist, E);
    scan1_kernel<<<nb, 256, 0, stream>>>(hist, N, row, bsum, nScan);
    scan2_kernel<<<1, 64, 0, stream>>>(bsum, nb);
    scan3_kernel<<<nb, 256, 0, stream>>>(row, bsum, cur, nScan, N);
    scatter_kernel<<<1024, 256, 0, stream>>>(srcA, dstA, cur, perm, srcp, E);

    #define UNIT(u) (Wt + (size_t)(u) * 32768)

    // ---- embedding MLP: G -> bx -> b2 -> bx ----
    gemm_mfma<<<g1grid, 256, 0, stream>>>(G,  UNIT(0), embb + 0,    bx, N, DD, 1);
    gemm_mfma<<<g1grid, 256, 0, stream>>>(bx, UNIT(1), embb + DD,   b2, N, DD, 1);
    gemm_mfma<<<g1grid, 256, 0, stream>>>(b2, UNIT(2), embb + 2*DD, bx, N, DD, 1);

    // ---- conv layer 0: x=bx -> out b2 ----
    gemm_mfma<<<g4grid, 256, 0, stream>>>(bx, UNIT(3), biasCat, bfused, N, 512, 0);
    edge_agg7<<<aggGrid, 256, 0, stream>>>(row, srcp, ea, perm,
                                           edgW + 0, edgb + 0, bfused, b2, N);

    // ---- conv layer 1: x=b2 -> out bx ----
    gemm_mfma<<<g4grid, 256, 0, stream>>>(b2, UNIT(7), biasCat + 512, bfused, N, 512, 0);
    edge_agg7<<<aggGrid, 256, 0, stream>>>(row, srcp, ea, perm,
                                           edgW + 21*DD, edgb + DD, bfused, bx, N);

    // ---- graph linears: bx -> b2 (relu) -> bx ----
    gemm_mfma<<<g1grid, 256, 0, stream>>>(bx, UNIT(11), g1b, b2, N, DD, 1);
    gemm_mfma<<<g1grid, 256, 0, stream>>>(b2, UNIT(12), g2b, bx, N, DD, 0);

    // ---- graph mean -> cvec ----
    hipMemsetAsync(gsum, 0, DD * sizeof(float), stream);
    colsum_kernel<<<256, DD, 0, stream>>>(bx, gsum, N);
    cvec_kernel<<<1, DD, 0, stream>>>(gsum, h1W, h1b, cvec, 1.0f / (float)N);

    // ---- head: h1 (bias=cvec, relu) -> b2 ; h2 -> bx ; h3 -> out ----
    gemm_mfma<<<g1grid, 256, 0, stream>>>(bx, UNIT(13), cvec, b2, N, DD, 1);
    gemm_mfma<<<g1grid, 256, 0, stream>>>(b2, UNIT(14), h2b, bx, N, DD, 1);
    head3_kernel<<<waveGrid, 256, 0, stream>>>(bx, h3W, h3b, (float*)d_out, N);
}

// Round 9
// 1839.470 us; speedup vs baseline: 1.0667x; 1.0667x over previous
//
#include <hip/hip_runtime.h>
#include <hip/hip_bf16.h>

#define DD 128

typedef __attribute__((ext_vector_type(8))) short bf16x8;
typedef __attribute__((ext_vector_type(4))) float f32x4;

// split 8 fp32 -> packed bf16 hi (truncate) and lo (truncate of residual)
__device__ __forceinline__ void cvt8(const float4 a0, const float4 a1,
                                     bf16x8& hi, bf16x8& lo)
{
    float af[8] = {a0.x, a0.y, a0.z, a0.w, a1.x, a1.y, a1.z, a1.w};
    union { unsigned int u[4]; bf16x8 v; } H, L;
    #pragma unroll
    for (int i = 0; i < 4; ++i) {
        unsigned int b0 = __float_as_uint(af[2*i]);
        unsigned int b1 = __float_as_uint(af[2*i+1]);
        unsigned int h0 = b0 & 0xFFFF0000u;
        unsigned int h1 = b1 & 0xFFFF0000u;
        H.u[i] = (h0 >> 16) | h1;
        float r0 = af[2*i]   - __uint_as_float(h0);
        float r1 = af[2*i+1] - __uint_as_float(h1);
        L.u[i] = (__float_as_uint(r0) >> 16) | (__float_as_uint(r1) & 0xFFFF0000u);
    }
    hi = H.v; lo = L.v;
}

__device__ __forceinline__ float bfhl(unsigned short h, unsigned short l)
{
    return __uint_as_float((unsigned int)h << 16) + __uint_as_float((unsigned int)l << 16);
}

// ABF: 0 = A fp32 [n][128] (cvt8), 1 = A bf16 hi/lo planes [n][256] ushort
// OBF: 0 = Y fp32 (ldY stride), 1 = Y bf16 hi/lo planes [n][256]
template<int ABF, int OBF>
__global__ __launch_bounds__(256) void gemm_t(
    const void* __restrict__ Xv, const unsigned short* __restrict__ Wt,
    const float* __restrict__ bias, void* __restrict__ Yv,
    int N, int ldY, int act)
{
    const int lane = threadIdx.x & 63;
    const int wid  = threadIdx.x >> 6;
    const int wr = wid >> 1, wc = wid & 1;
    const int row0 = blockIdx.x * 128 + wr * 64;
    const int cb   = blockIdx.y;
    const unsigned short* WtH = Wt + (size_t)cb * 32768;
    const unsigned short* WtL = WtH + 16384;

    const int l15 = lane & 15;
    const int kg  = (lane >> 4) * 8;

    f32x4 acc[4][4] = {};

    int arow[4];
    #pragma unroll
    for (int mi = 0; mi < 4; ++mi) {
        int r = row0 + mi * 16 + l15;
        arow[mi] = r < N ? r : N - 1;
    }

    #pragma unroll
    for (int kc = 0; kc < 4; ++kc) {
        const int kb = kc * 32 + kg;
        bf16x8 ah[4], al[4], bh[4], bl[4];
        #pragma unroll
        for (int mi = 0; mi < 4; ++mi) {
            if (ABF) {
                const unsigned short* p = (const unsigned short*)Xv + (size_t)arow[mi] * 256 + kb;
                ah[mi] = *(const bf16x8*)p;
                al[mi] = *(const bf16x8*)(p + 128);
            } else {
                const float* p = (const float*)Xv + (size_t)arow[mi] * DD + kb;
                float4 a0 = *(const float4*)p;
                float4 a1 = *(const float4*)(p + 4);
                cvt8(a0, a1, ah[mi], al[mi]);
            }
        }
        #pragma unroll
        for (int ni = 0; ni < 4; ++ni) {
            int m = wc * 64 + ni * 16 + l15;
            bh[ni] = *(const bf16x8*)(WtH + (size_t)m * DD + kb);
            bl[ni] = *(const bf16x8*)(WtL + (size_t)m * DD + kb);
        }
        #pragma unroll
        for (int mi = 0; mi < 4; ++mi)
            #pragma unroll
            for (int ni = 0; ni < 4; ++ni) {
                acc[mi][ni] = __builtin_amdgcn_mfma_f32_16x16x32_bf16(ah[mi], bh[ni], acc[mi][ni], 0, 0, 0);
                acc[mi][ni] = __builtin_amdgcn_mfma_f32_16x16x32_bf16(ah[mi], bl[ni], acc[mi][ni], 0, 0, 0);
                acc[mi][ni] = __builtin_amdgcn_mfma_f32_16x16x32_bf16(al[mi], bh[ni], acc[mi][ni], 0, 0, 0);
            }
    }

    const int colW = cb * 128 + wc * 64;
    #pragma unroll
    for (int ni = 0; ni < 4; ++ni) {
        const int col = colW + ni * 16 + l15;
        float bv = bias[col];
        #pragma unroll
        for (int mi = 0; mi < 4; ++mi) {
            #pragma unroll
            for (int r = 0; r < 4; ++r) {
                int row = row0 + mi * 16 + (lane >> 4) * 4 + r;
                if (row < N) {
                    float v = acc[mi][ni][r] + bv;
                    if (act) v = fmaxf(v, 0.f);
                    if (OBF) {
                        unsigned short* Yb = (unsigned short*)Yv;
                        unsigned int uv = __float_as_uint(v);
                        unsigned int h = uv & 0xFFFF0000u;
                        float rr = v - __uint_as_float(h);
                        Yb[(size_t)row * 256 + col]       = (unsigned short)(h >> 16);
                        Yb[(size_t)row * 256 + 128 + col] = (unsigned short)(__float_as_uint(rr) >> 16);
                    } else {
                        ((float*)Yv)[(size_t)row * ldY + col] = v;
                    }
                }
            }
        }
    }
}

// one-time: transpose+split weight units to bf16 hi/lo [m][k].
__global__ __launch_bounds__(256) void prep_weights(
    const float* __restrict__ embW, const float* __restrict__ keyW,
    const float* __restrict__ qryW, const float* __restrict__ valW,
    const float* __restrict__ skpW, const float* __restrict__ g1W,
    const float* __restrict__ g2W, const float* __restrict__ h1W,
    const float* __restrict__ h2W,
    const float* __restrict__ keyb, const float* __restrict__ qryb,
    const float* __restrict__ valb, const float* __restrict__ skpb,
    unsigned short* __restrict__ Wt, float* __restrict__ biasCat)
{
    const int u = blockIdx.x;   // 0..14
    const int t = threadIdx.x;
    __shared__ float T[128][129];

    const float* src;
    if (u < 3)       src = embW + (size_t)u * 16384;
    else if (u < 7)  { const float* p[4] = {keyW, qryW, valW, skpW}; src = p[u - 3]; }
    else if (u < 11) { const float* p[4] = {keyW, qryW, valW, skpW}; src = p[u - 7] + 16384; }
    else if (u == 11) src = g1W;
    else if (u == 12) src = g2W;
    else if (u == 13) src = h1W;
    else              src = h2W;

    #pragma unroll
    for (int i = 0; i < 64; ++i) {
        int idx = t + 256 * i;
        T[idx >> 7][idx & 127] = src[idx];
    }
    __syncthreads();

    unsigned short* dH = Wt + (size_t)u * 32768;
    unsigned short* dL = dH + 16384;
    const int m = t >> 1, kbase = (t & 1) * 64;
    for (int j = 0; j < 64; ++j) {
        int k = kbase + j;
        float a = T[k][m];
        unsigned int b = __float_as_uint(a);
        unsigned int h = b & 0xFFFF0000u;
        float r = a - __uint_as_float(h);
        dH[m * 128 + k] = (unsigned short)(h >> 16);
        dL[m * 128 + k] = (unsigned short)(__float_as_uint(r) >> 16);
    }

    if (u == 0) {
        for (int x = t; x < 1024; x += 256) {
            int L = x >> 9, c = x & 511;
            const float* bp = (c < 128) ? keyb : (c < 256) ? qryb : (c < 384) ? valb : skpb;
            biasCat[x] = bp[L * 128 + (c & 127)];
        }
    }
}

// ---------------- CSR build ----------------
__global__ void hist_kernel(const int* __restrict__ dstA, int* __restrict__ hist, int E)
{
    for (int e = blockIdx.x * blockDim.x + threadIdx.x; e < E;
         e += gridDim.x * blockDim.x)
        atomicAdd(&hist[dstA[e]], 1);
}

__global__ __launch_bounds__(256) void scan1_kernel(
    const int* __restrict__ in, int n_in,
    int* __restrict__ out, int* __restrict__ bsum, int n)
{
    __shared__ int wtot[4];
    const int t = threadIdx.x, lane = t & 63, wv = t >> 6;
    const int base = blockIdx.x * 1024 + t * 4;
    int v[4]; int sum = 0;
    #pragma unroll
    for (int j = 0; j < 4; ++j) {
        int idx = base + j;
        v[j] = (idx < n_in) ? in[idx] : 0;
        sum += v[j];
    }
    int incl = sum;
    #pragma unroll
    for (int d = 1; d < 64; d <<= 1) {
        int y = __shfl_up(incl, d, 64);
        if (lane >= d) incl += y;
    }
    if (lane == 63) wtot[wv] = incl;
    __syncthreads();
    int woff = 0;
    for (int w = 0; w < wv; ++w) woff += wtot[w];
    int run = woff + incl - sum;
    #pragma unroll
    for (int j = 0; j < 4; ++j) {
        int idx = base + j;
        if (idx < n) out[idx] = run;
        run += v[j];
    }
    if (t == 0)
        bsum[blockIdx.x] = wtot[0] + wtot[1] + wtot[2] + wtot[3];
}

__global__ void scan2_kernel(int* __restrict__ bsum, int nb)
{
    if (blockIdx.x == 0 && threadIdx.x == 0) {
        int run = 0;
        for (int i = 0; i < nb; ++i) { int t = bsum[i]; bsum[i] = run; run += t; }
    }
}

__global__ __launch_bounds__(256) void scan3_kernel(
    int* __restrict__ out, const int* __restrict__ bsum,
    int* __restrict__ cursor, int n, int n_nodes)
{
    const int base = blockIdx.x * 1024 + threadIdx.x * 4;
    const int add = bsum[blockIdx.x];
    #pragma unroll
    for (int j = 0; j < 4; ++j) {
        int idx = base + j;
        if (idx < n) {
            int vv = out[idx] + add;
            out[idx] = vv;
            if (idx < n_nodes) cursor[idx] = vv;
        }
    }
}

__global__ void scatter_kernel(const int* __restrict__ srcA, const int* __restrict__ dstA,
                               int* __restrict__ cursor, int* __restrict__ perm,
                               int* __restrict__ srcp, int E)
{
    for (int e = blockIdx.x * blockDim.x + threadIdx.x; e < E;
         e += gridDim.x * blockDim.x) {
        int d = dstA[e];
        int pos = atomicAdd(&cursor[d], 1);
        perm[pos] = e;
        srcp[pos] = srcA[e];
    }
}

// ---------------- edge aggregation: wave per dst (round-7 structure), bf16 out ------
// fused layout per row: [K | Q | V | Sk] (4 x 128); X out = bf16 hi/lo planes [n][256]
__global__ __launch_bounds__(256) void edge_agg6(
    const int* __restrict__ row_ptr, const int* __restrict__ srcp,
    const float* __restrict__ ea, const int* __restrict__ perm,
    const float* __restrict__ We, const float* __restrict__ be,
    const float* __restrict__ fused, unsigned short* __restrict__ Xb, int N)
{
    const int wv = threadIdx.x >> 6, lane = threadIdx.x & 63;
    const int d = blockIdx.x * 4 + wv;
    if (d >= N) return;
    const int c = lane * 2;

    float2 w[21];
    #pragma unroll
    for (int j = 0; j < 21; ++j)
        w[j] = *(const float2*)(We + j * DD + c);
    const float2 b2 = *(const float2*)(be + c);
    const float2 kd = *(const float2*)(fused + (size_t)d * 512 + c);
    const float2 sk = *(const float2*)(fused + (size_t)d * 512 + 384 + c);

    float ax = 0.f, ay = 0.f;
    const int i0 = row_ptr[d], i1 = row_ptr[d + 1];

    for (int i = i0; i < i1; i += 2) {
        const int iA = i;
        const int iB = (i + 1 < i1) ? i + 1 : i1 - 1;
        const float wgtB = (i + 1 < i1) ? 1.f : 0.f;

        const int sA = srcp[iA], sB = srcp[iB];
        const int pA = perm[iA], pB = perm[iB];

        const float* eA = ea + (size_t)pA * 21;
        const float* eB = ea + (size_t)pB * 21;
        float4 A0 = *(const float4*)(eA);      float4 B0 = *(const float4*)(eB);
        float4 A1 = *(const float4*)(eA + 4);  float4 B1 = *(const float4*)(eB + 4);
        float4 A2 = *(const float4*)(eA + 8);  float4 B2 = *(const float4*)(eB + 8);
        float4 A3 = *(const float4*)(eA + 12); float4 B3 = *(const float4*)(eB + 12);
        float4 A4 = *(const float4*)(eA + 16); float4 B4 = *(const float4*)(eB + 16);
        float A5 = eA[20], B5 = eB[20];

        const float* fpA = fused + (size_t)sA * 512;
        const float* fpB = fused + (size_t)sB * 512;
        float2 qA = *(const float2*)(fpA + 128 + c);
        float2 vA = *(const float2*)(fpA + 256 + c);
        float2 qB = *(const float2*)(fpB + 128 + c);
        float2 vB = *(const float2*)(fpB + 256 + c);

        float aA[21] = {A0.x,A0.y,A0.z,A0.w, A1.x,A1.y,A1.z,A1.w,
                        A2.x,A2.y,A2.z,A2.w, A3.x,A3.y,A3.z,A3.w,
                        A4.x,A4.y,A4.z,A4.w, A5};
        float aB[21] = {B0.x,B0.y,B0.z,B0.w, B1.x,B1.y,B1.z,B1.w,
                        B2.x,B2.y,B2.z,B2.w, B3.x,B3.y,B3.z,B3.w,
                        B4.x,B4.y,B4.z,B4.w, B5};

        float pxA[4] = {0,0,0,0}, pyA[4] = {0,0,0,0};
        float pxB[4] = {0,0,0,0}, pyB[4] = {0,0,0,0};
        #pragma unroll
        for (int j = 0; j < 21; ++j) {
            int s = j & 3;
            pxA[s] = fmaf(aA[j], w[j].x, pxA[s]);
            pyA[s] = fmaf(aA[j], w[j].y, pyA[s]);
            pxB[s] = fmaf(aB[j], w[j].x, pxB[s]);
            pyB[s] = fmaf(aB[j], w[j].y, pyB[s]);
        }
        float exA = (pxA[0] + pxA[1]) + (pxA[2] + pxA[3]) + b2.x;
        float eyA = (pyA[0] + pyA[1]) + (pyA[2] + pyA[3]) + b2.y;
        float exB = (pxB[0] + pxB[1]) + (pxB[2] + pxB[3]) + b2.x;
        float eyB = (pyB[0] + pyB[1]) + (pyB[2] + pyB[3]) + b2.y;

        float zxA = kd.x + qA.x + exA;
        float zyA = kd.y + qA.y + eyA;
        float zxB = kd.x + qB.x + exB;
        float zyB = kd.y + qB.y + eyB;

        float gxA = 1.f / (1.f + __expf(-zxA));
        float gyA = 1.f / (1.f + __expf(-zyA));
        float gxB = wgtB / (1.f + __expf(-zxB));
        float gyB = wgtB / (1.f + __expf(-zyB));

        ax = fmaf(gxA, vA.x, ax);
        ay = fmaf(gyA, vA.y, ay);
        ax = fmaf(gxB, vB.x, ax);
        ay = fmaf(gyB, vB.y, ay);
    }

    float ox = fmaxf(ax + sk.x, 0.f);
    float oy = fmaxf(ay + sk.y, 0.f);
    unsigned int ux = __float_as_uint(ox), hx = ux & 0xFFFF0000u;
    unsigned int uy = __float_as_uint(oy), hy = uy & 0xFFFF0000u;
    float rx = ox - __uint_as_float(hx);
    float ry = oy - __uint_as_float(hy);
    unsigned short* Xr = Xb + (size_t)d * 256;
    *(ushort2*)(Xr + c) = make_ushort2((unsigned short)(hx >> 16), (unsigned short)(hy >> 16));
    *(ushort2*)(Xr + 128 + c) = make_ushort2((unsigned short)(__float_as_uint(rx) >> 16),
                                             (unsigned short)(__float_as_uint(ry) >> 16));
}

// column sums of x (bf16 planes) into gsum[128] (gsum pre-zeroed)
__global__ void colsum_bf(const unsigned short* __restrict__ x, float* __restrict__ gsum, int N)
{
    const int c = threadIdx.x;
    float acc = 0.f;
    for (int r = blockIdx.x; r < N; r += gridDim.x)
        acc += bfhl(x[(size_t)r * 256 + c], x[(size_t)r * 256 + 128 + c]);
    atomicAdd(&gsum[c], acc);
}

__global__ void cvec_kernel(const float* __restrict__ gsum, const float* __restrict__ h1W,
                            const float* __restrict__ h1b, float* __restrict__ cvec, float invN)
{
    const int m = threadIdx.x;
    float acc = h1b[m];
    for (int k = 0; k < 128; ++k)
        acc = fmaf(gsum[k] * invN, h1W[(size_t)(128 + k) * DD + m], acc);
    cvec[m] = acc;
}

__global__ __launch_bounds__(256) void head3_bf(
    const unsigned short* __restrict__ x, const float* __restrict__ w,
    const float* __restrict__ b, float* __restrict__ out, int N)
{
    const int wave = threadIdx.x >> 6;
    const int lane = threadIdx.x & 63;
    const long n = (long)blockIdx.x * 4 + wave;
    if (n >= N) return;
    const unsigned short* xr = x + (size_t)n * 256;
    float v0 = bfhl(xr[lane], xr[128 + lane]);
    float v1 = bfhl(xr[64 + lane], xr[192 + lane]);
    float acc = v0 * w[lane] + v1 * w[64 + lane];
    #pragma unroll
    for (int off = 32; off > 0; off >>= 1)
        acc += __shfl_down(acc, off, 64);
    if (lane == 0) out[n] = acc + b[0];
}

extern "C" void kernel_launch(void* const* d_in, const int* in_sizes, int n_in,
                              void* d_out, int out_size, void* d_ws, size_t ws_size,
                              hipStream_t stream)
{
    const float* G    = (const float*)d_in[0];
    const int*   ei   = (const int*)  d_in[1];
    const float* ea   = (const float*)d_in[2];
    const float* embW = (const float*)d_in[3];
    const float* embb = (const float*)d_in[4];
    const float* keyW = (const float*)d_in[5];
    const float* keyb = (const float*)d_in[6];
    const float* qryW = (const float*)d_in[7];
    const float* qryb = (const float*)d_in[8];
    const float* valW = (const float*)d_in[9];
    const float* valb = (const float*)d_in[10];
    const float* skpW = (const float*)d_in[11];
    const float* skpb = (const float*)d_in[12];
    const float* edgW = (const float*)d_in[13];
    const float* edgb = (const float*)d_in[14];
    const float* g1W  = (const float*)d_in[15];
    const float* g1b  = (const float*)d_in[16];
    const float* g2W  = (const float*)d_in[17];
    const float* g2b  = (const float*)d_in[18];
    const float* h1W  = (const float*)d_in[19];
    const float* h1b  = (const float*)d_in[20];
    const float* h2W  = (const float*)d_in[21];
    const float* h2b  = (const float*)d_in[22];
    const float* h3W  = (const float*)d_in[23];
    const float* h3b  = (const float*)d_in[24];

    const int N = in_sizes[0] / DD;    // 100000
    const int E = in_sizes[2] / 21;    // 1000000
    const int* srcA = ei;
    const int* dstA = ei + E;

    unsigned short* bxbf = (unsigned short*)d_ws;        // [N][256] bf16 planes
    unsigned short* b2bf = bxbf + (size_t)N * 256;       // [N][256]
    float* bfused = (float*)(b2bf + (size_t)N * 256);    // [N][512]  (K | Q | V | Sk)
    float* gsum   = bfused + (size_t)N * 512;            // 128
    float* cvec   = gsum + DD;                           // 128
    float* biasCat= cvec + DD;                           // 1024
    unsigned short* Wt = (unsigned short*)(biasCat + 1024);  // 15*32768 ushorts
    int* hist = (int*)((char*)Wt + (size_t)15 * 32768 * 2);  // N
    int* row  = hist + N;              // N+1
    int* cur  = row + N + 1;           // N
    int* bsum = cur + N;               // 128
    int* perm = bsum + 128;            // E
    int* srcp = perm + E;              // E

    const dim3 g1grid((N + 127) / 128, 1);
    const dim3 g4grid((N + 127) / 128, 4);
    const int aggGrid = (N + 3) / 4;
    const int waveGrid = (N + 3) / 4;
    const int nScan = N + 1;
    const int nb = (nScan + 1023) / 1024;

    // ---- weight prep + CSR build ----
    prep_weights<<<15, 256, 0, stream>>>(embW, keyW, qryW, valW, skpW,
                                         g1W, g2W, h1W, h2W,
                                         keyb, qryb, valb, skpb, Wt, biasCat);
    hipMemsetAsync(hist, 0, (size_t)N * sizeof(int), stream);
    hist_kernel<<<1024, 256, 0, stream>>>(dstA, hist, E);
    scan1_kernel<<<nb, 256, 0, stream>>>(hist, N, row, bsum, nScan);
    scan2_kernel<<<1, 64, 0, stream>>>(bsum, nb);
    scan3_kernel<<<nb, 256, 0, stream>>>(row, bsum, cur, nScan, N);
    scatter_kernel<<<1024, 256, 0, stream>>>(srcA, dstA, cur, perm, srcp, E);

    #define UNIT(u) (Wt + (size_t)(u) * 32768)

    // ---- embedding MLP: G(fp32) -> bxbf -> b2bf -> bxbf ----
    gemm_t<0,1><<<g1grid, 256, 0, stream>>>(G,    UNIT(0), embb + 0,    bxbf, N, 0, 1);
    gemm_t<1,1><<<g1grid, 256, 0, stream>>>(bxbf, UNIT(1), embb + DD,   b2bf, N, 0, 1);
    gemm_t<1,1><<<g1grid, 256, 0, stream>>>(b2bf, UNIT(2), embb + 2*DD, bxbf, N, 0, 1);

    // ---- conv layer 0: x=bxbf -> fused(fp32) -> edges -> b2bf ----
    gemm_t<1,0><<<g4grid, 256, 0, stream>>>(bxbf, UNIT(3), biasCat, bfused, N, 512, 0);
    edge_agg6<<<aggGrid, 256, 0, stream>>>(row, srcp, ea, perm,
                                           edgW + 0, edgb + 0, bfused, b2bf, N);

    // ---- conv layer 1: x=b2bf -> fused -> edges -> bxbf ----
    gemm_t<1,0><<<g4grid, 256, 0, stream>>>(b2bf, UNIT(7), biasCat + 512, bfused, N, 512, 0);
    edge_agg6<<<aggGrid, 256, 0, stream>>>(row, srcp, ea, perm,
                                           edgW + 21*DD, edgb + DD, bfused, bxbf, N);

    // ---- graph linears: bxbf -> b2bf (relu) -> bxbf ----
    gemm_t<1,1><<<g1grid, 256, 0, stream>>>(bxbf, UNIT(11), g1b, b2bf, N, 0, 1);
    gemm_t<1,1><<<g1grid, 256, 0, stream>>>(b2bf, UNIT(12), g2b, bxbf, N, 0, 0);

    // ---- graph mean -> cvec ----
    hipMemsetAsync(gsum, 0, DD * sizeof(float), stream);
    colsum_bf<<<256, DD, 0, stream>>>(bxbf, gsum, N);
    cvec_kernel<<<1, DD, 0, stream>>>(gsum, h1W, h1b, cvec, 1.0f / (float)N);

    // ---- head: h1 (bias=cvec, relu) -> b2bf ; h2 -> bxbf ; h3 -> out ----
    gemm_t<1,1><<<g1grid, 256, 0, stream>>>(bxbf, UNIT(13), cvec, b2bf, N, 0, 1);
    gemm_t<1,1><<<g1grid, 256, 0, stream>>>(b2bf, UNIT(14), h2b, bxbf, N, 0, 1);
    head3_bf<<<waveGrid, 256, 0, stream>>>(bxbf, h3W, h3b, (float*)d_out, N);
}

// Round 10
// 1510.163 us; speedup vs baseline: 1.2993x; 1.2181x over previous
//
#include <hip/hip_runtime.h>
#include <hip/hip_bf16.h>

#define DD 128
#define LW 136

typedef __attribute__((ext_vector_type(8))) short bf16x8;
typedef __attribute__((ext_vector_type(4))) float f32x4;

// split 8 fp32 -> packed bf16 hi (truncate) and lo (truncate of residual)
__device__ __forceinline__ void cvt8(const float4 a0, const float4 a1,
                                     bf16x8& hi, bf16x8& lo)
{
    float af[8] = {a0.x, a0.y, a0.z, a0.w, a1.x, a1.y, a1.z, a1.w};
    union { unsigned int u[4]; bf16x8 v; } H, L;
    #pragma unroll
    for (int i = 0; i < 4; ++i) {
        unsigned int b0 = __float_as_uint(af[2*i]);
        unsigned int b1 = __float_as_uint(af[2*i+1]);
        unsigned int h0 = b0 & 0xFFFF0000u;
        unsigned int h1 = b1 & 0xFFFF0000u;
        H.u[i] = (h0 >> 16) | h1;
        float r0 = af[2*i]   - __uint_as_float(h0);
        float r1 = af[2*i+1] - __uint_as_float(h1);
        L.u[i] = (__float_as_uint(r0) >> 16) | (__float_as_uint(r1) & 0xFFFF0000u);
    }
    hi = H.v; lo = L.v;
}

// ---------------- kqvs GEMM (round-7 proven): 128-tile, fp32 in/out ----------------
__global__ __launch_bounds__(256) void gemm_mfma(
    const float* __restrict__ X, const unsigned short* __restrict__ Wt,
    const float* __restrict__ bias, float* __restrict__ Y,
    int N, int ldY, int act)
{
    const int lane = threadIdx.x & 63;
    const int wid  = threadIdx.x >> 6;
    const int wr = wid >> 1, wc = wid & 1;
    const int row0 = blockIdx.x * 128 + wr * 64;
    const int cb   = blockIdx.y;
    const unsigned short* WtH = Wt + (size_t)cb * 32768;
    const unsigned short* WtL = WtH + 16384;

    const int l15 = lane & 15;
    const int kg  = (lane >> 4) * 8;

    f32x4 acc[4][4] = {};

    int arow[4];
    #pragma unroll
    for (int mi = 0; mi < 4; ++mi) {
        int r = row0 + mi * 16 + l15;
        arow[mi] = r < N ? r : N - 1;
    }

    #pragma unroll
    for (int kc = 0; kc < 4; ++kc) {
        const int kb = kc * 32 + kg;
        bf16x8 ah[4], al[4], bh[4], bl[4];
        #pragma unroll
        for (int mi = 0; mi < 4; ++mi) {
            const float* p = X + (size_t)arow[mi] * DD + kb;
            float4 a0 = *(const float4*)p;
            float4 a1 = *(const float4*)(p + 4);
            cvt8(a0, a1, ah[mi], al[mi]);
        }
        #pragma unroll
        for (int ni = 0; ni < 4; ++ni) {
            int m = wc * 64 + ni * 16 + l15;
            bh[ni] = *(const bf16x8*)(WtH + (size_t)m * DD + kb);
            bl[ni] = *(const bf16x8*)(WtL + (size_t)m * DD + kb);
        }
        #pragma unroll
        for (int mi = 0; mi < 4; ++mi)
            #pragma unroll
            for (int ni = 0; ni < 4; ++ni) {
                acc[mi][ni] = __builtin_amdgcn_mfma_f32_16x16x32_bf16(ah[mi], bh[ni], acc[mi][ni], 0, 0, 0);
                acc[mi][ni] = __builtin_amdgcn_mfma_f32_16x16x32_bf16(ah[mi], bl[ni], acc[mi][ni], 0, 0, 0);
                acc[mi][ni] = __builtin_amdgcn_mfma_f32_16x16x32_bf16(al[mi], bh[ni], acc[mi][ni], 0, 0, 0);
            }
    }

    const int colW = cb * 128 + wc * 64;
    #pragma unroll
    for (int ni = 0; ni < 4; ++ni) {
        float bv = bias[colW + ni * 16 + l15];
        #pragma unroll
        for (int mi = 0; mi < 4; ++mi) {
            #pragma unroll
            for (int r = 0; r < 4; ++r) {
                int row = row0 + mi * 16 + (lane >> 4) * 4 + r;
                if (row < N) {
                    float v = acc[mi][ni][r] + bv;
                    Y[(size_t)row * ldY + colW + ni * 16 + l15] = act ? fmaxf(v, 0.f) : v;
                }
            }
        }
    }
}

// ---------------- fused-MLP building blocks: 64-row tile, 4 waves x 32 cols --------
__device__ __forceinline__ void mfma_step(
    const unsigned short* __restrict__ WH, const unsigned short* __restrict__ WL,
    int wavecol, int l15, int kb,
    const bf16x8 ah[4], const bf16x8 al[4], f32x4 acc[4][2])
{
    bf16x8 bh[2], bl[2];
    #pragma unroll
    for (int ni = 0; ni < 2; ++ni) {
        int m = wavecol + ni * 16 + l15;
        bh[ni] = *(const bf16x8*)(WH + (size_t)m * DD + kb);
        bl[ni] = *(const bf16x8*)(WL + (size_t)m * DD + kb);
    }
    #pragma unroll
    for (int mi = 0; mi < 4; ++mi)
        #pragma unroll
        for (int ni = 0; ni < 2; ++ni) {
            acc[mi][ni] = __builtin_amdgcn_mfma_f32_16x16x32_bf16(ah[mi], bh[ni], acc[mi][ni], 0, 0, 0);
            acc[mi][ni] = __builtin_amdgcn_mfma_f32_16x16x32_bf16(ah[mi], bl[ni], acc[mi][ni], 0, 0, 0);
            acc[mi][ni] = __builtin_amdgcn_mfma_f32_16x16x32_bf16(al[mi], bh[ni], acc[mi][ni], 0, 0, 0);
        }
}

__device__ __forceinline__ void glb_layer(
    const float* __restrict__ X, const int arow[4],
    const unsigned short* __restrict__ WU,
    int wavecol, int l15, int kg, f32x4 acc[4][2])
{
    const unsigned short* WH = WU;
    const unsigned short* WL = WU + 16384;
    #pragma unroll
    for (int kc = 0; kc < 4; ++kc) {
        const int kb = kc * 32 + kg;
        bf16x8 ah[4], al[4];
        #pragma unroll
        for (int mi = 0; mi < 4; ++mi) {
            const float* p = X + (size_t)arow[mi] * DD + kb;
            float4 a0 = *(const float4*)p;
            float4 a1 = *(const float4*)(p + 4);
            cvt8(a0, a1, ah[mi], al[mi]);
        }
        mfma_step(WH, WL, wavecol, l15, kb, ah, al, acc);
    }
}

__device__ __forceinline__ void lds_layer(
    const unsigned short (*AH)[LW], const unsigned short (*AL)[LW],
    const unsigned short* __restrict__ WU,
    int wavecol, int l15, int kg, f32x4 acc[4][2])
{
    const unsigned short* WH = WU;
    const unsigned short* WL = WU + 16384;
    #pragma unroll
    for (int kc = 0; kc < 4; ++kc) {
        const int kb = kc * 32 + kg;
        bf16x8 ah[4], al[4];
        #pragma unroll
        for (int mi = 0; mi < 4; ++mi) {
            ah[mi] = *(const bf16x8*)&AH[mi * 16 + l15][kb];
            al[mi] = *(const bf16x8*)&AL[mi * 16 + l15][kb];
        }
        mfma_step(WH, WL, wavecol, l15, kb, ah, al, acc);
    }
}

__device__ __forceinline__ void epi_lds(
    const f32x4 acc[4][2], unsigned short (*AH)[LW], unsigned short (*AL)[LW],
    const float* __restrict__ bias, int wavecol, int l15, int rg, int relu)
{
    #pragma unroll
    for (int ni = 0; ni < 2; ++ni) {
        const int col = wavecol + ni * 16 + l15;
        const float bv = bias[col];
        #pragma unroll
        for (int mi = 0; mi < 4; ++mi)
            #pragma unroll
            for (int r = 0; r < 4; ++r) {
                const int row = mi * 16 + rg + r;
                float v = acc[mi][ni][r] + bv;
                if (relu) v = fmaxf(v, 0.f);
                unsigned int u = __float_as_uint(v), h = u & 0xFFFF0000u;
                float res = v - __uint_as_float(h);
                AH[row][col] = (unsigned short)(h >> 16);
                AL[row][col] = (unsigned short)(__float_as_uint(res) >> 16);
            }
    }
}

// ---- fused emb: relu(relu(relu(G@W0+b0)@W1+b1)@W2+b2) -> Y fp32 ----
__global__ __launch_bounds__(256) void fused_emb3(
    const float* __restrict__ G, const unsigned short* __restrict__ Wt,
    const float* __restrict__ embb, float* __restrict__ Y, int N)
{
    __shared__ unsigned short AH[64][LW], AL[64][LW];
    const int lane = threadIdx.x & 63, wid = threadIdx.x >> 6;
    const int wavecol = wid * 32;
    const int l15 = lane & 15, kg = (lane >> 4) * 8, rg = (lane >> 4) * 4;
    const int row0 = blockIdx.x * 64;

    int arow[4];
    #pragma unroll
    for (int mi = 0; mi < 4; ++mi) {
        int r = row0 + mi * 16 + l15;
        arow[mi] = r < N ? r : N - 1;
    }

    f32x4 acc[4][2] = {};
    glb_layer(G, arow, Wt, wavecol, l15, kg, acc);
    epi_lds(acc, AH, AL, embb, wavecol, l15, rg, 1);
    __syncthreads();

    #pragma unroll
    for (int mi = 0; mi < 4; ++mi)
        #pragma unroll
        for (int ni = 0; ni < 2; ++ni) acc[mi][ni] = (f32x4){0,0,0,0};
    lds_layer(AH, AL, Wt + 32768, wavecol, l15, kg, acc);
    __syncthreads();
    epi_lds(acc, AH, AL, embb + 128, wavecol, l15, rg, 1);
    __syncthreads();

    #pragma unroll
    for (int mi = 0; mi < 4; ++mi)
        #pragma unroll
        for (int ni = 0; ni < 2; ++ni) acc[mi][ni] = (f32x4){0,0,0,0};
    lds_layer(AH, AL, Wt + 65536, wavecol, l15, kg, acc);

    #pragma unroll
    for (int ni = 0; ni < 2; ++ni) {
        const int col = wavecol + ni * 16 + l15;
        const float bv = embb[256 + col];
        #pragma unroll
        for (int mi = 0; mi < 4; ++mi)
            #pragma unroll
            for (int r = 0; r < 4; ++r) {
                int row = row0 + mi * 16 + rg + r;
                if (row < N)
                    Y[(size_t)row * DD + col] = fmaxf(acc[mi][ni][r] + bv, 0.f);
            }
    }
}

// ---- fused g1,g2 + column-sum: Y = relu(X@g1+b1)@g2+b2 ; gsum += colsum(Y) ----
__global__ __launch_bounds__(256) void fused_g12(
    const float* __restrict__ X, const unsigned short* __restrict__ Wt,
    const float* __restrict__ g1b, const float* __restrict__ g2b,
    float* __restrict__ Y, float* __restrict__ gsum, int N)
{
    __shared__ unsigned short AH[64][LW], AL[64][LW];
    __shared__ float csum[128];
    const int tid = threadIdx.x;
    const int lane = tid & 63, wid = tid >> 6;
    const int wavecol = wid * 32;
    const int l15 = lane & 15, kg = (lane >> 4) * 8, rg = (lane >> 4) * 4;
    const int row0 = blockIdx.x * 64;

    if (tid < 128) csum[tid] = 0.f;

    int arow[4];
    #pragma unroll
    for (int mi = 0; mi < 4; ++mi) {
        int r = row0 + mi * 16 + l15;
        arow[mi] = r < N ? r : N - 1;
    }

    f32x4 acc[4][2] = {};
    glb_layer(X, arow, Wt, wavecol, l15, kg, acc);
    epi_lds(acc, AH, AL, g1b, wavecol, l15, rg, 1);
    __syncthreads();

    #pragma unroll
    for (int mi = 0; mi < 4; ++mi)
        #pragma unroll
        for (int ni = 0; ni < 2; ++ni) acc[mi][ni] = (f32x4){0,0,0,0};
    lds_layer(AH, AL, Wt + 32768, wavecol, l15, kg, acc);

    #pragma unroll
    for (int ni = 0; ni < 2; ++ni) {
        const int col = wavecol + ni * 16 + l15;
        const float bv = g2b[col];
        float part = 0.f;
        #pragma unroll
        for (int mi = 0; mi < 4; ++mi)
            #pragma unroll
            for (int r = 0; r < 4; ++r) {
                int row = row0 + mi * 16 + rg + r;
                if (row < N) {
                    float v = acc[mi][ni][r] + bv;
                    Y[(size_t)row * DD + col] = v;
                    part += v;
                }
            }
        atomicAdd(&csum[col], part);
    }
    __syncthreads();
    if (tid < 128) atomicAdd(&gsum[tid], csum[tid]);
}

// ---- fused head: u=relu(X@h1+cvec); u=relu(u@h2+b2); out = u.h3w + h3b ----
__global__ __launch_bounds__(256) void fused_head(
    const float* __restrict__ X, const unsigned short* __restrict__ Wt,
    const float* __restrict__ cvec, const float* __restrict__ h2b,
    const float* __restrict__ h3w, const float* __restrict__ h3b,
    float* __restrict__ out, int N)
{
    __shared__ unsigned short AH[64][LW], AL[64][LW];
    const int tid = threadIdx.x;
    const int lane = tid & 63, wid = tid >> 6;
    const int wavecol = wid * 32;
    const int l15 = lane & 15, kg = (lane >> 4) * 8, rg = (lane >> 4) * 4;
    const int row0 = blockIdx.x * 64;

    int arow[4];
    #pragma unroll
    for (int mi = 0; mi < 4; ++mi) {
        int r = row0 + mi * 16 + l15;
        arow[mi] = r < N ? r : N - 1;
    }

    f32x4 acc[4][2] = {};
    glb_layer(X, arow, Wt, wavecol, l15, kg, acc);
    epi_lds(acc, AH, AL, cvec, wavecol, l15, rg, 1);
    __syncthreads();

    #pragma unroll
    for (int mi = 0; mi < 4; ++mi)
        #pragma unroll
        for (int ni = 0; ni < 2; ++ni) acc[mi][ni] = (f32x4){0,0,0,0};
    lds_layer(AH, AL, Wt + 32768, wavecol, l15, kg, acc);
    __syncthreads();
    epi_lds(acc, AH, AL, h2b, wavecol, l15, rg, 1);
    __syncthreads();

    // h3 dot: thread t -> row t>>2, col segment (t&3)*32
    const int row = tid >> 2, seg = tid & 3;
    float s = 0.f;
    #pragma unroll 8
    for (int j = 0; j < 32; ++j) {
        int col = seg * 32 + j;
        float xv = __uint_as_float((unsigned int)AH[row][col] << 16)
                 + __uint_as_float((unsigned int)AL[row][col] << 16);
        s = fmaf(xv, h3w[col], s);
    }
    s += __shfl_xor(s, 1, 64);
    s += __shfl_xor(s, 2, 64);
    if (seg == 0 && row0 + row < N) out[row0 + row] = s + h3b[0];
}

// one-time: transpose+split weight units to bf16 hi/lo [m][k].
__global__ __launch_bounds__(256) void prep_weights(
    const float* __restrict__ embW, const float* __restrict__ keyW,
    const float* __restrict__ qryW, const float* __restrict__ valW,
    const float* __restrict__ skpW, const float* __restrict__ g1W,
    const float* __restrict__ g2W, const float* __restrict__ h1W,
    const float* __restrict__ h2W,
    const float* __restrict__ keyb, const float* __restrict__ qryb,
    const float* __restrict__ valb, const float* __restrict__ skpb,
    unsigned short* __restrict__ Wt, float* __restrict__ biasCat)
{
    const int u = blockIdx.x;   // 0..14
    const int t = threadIdx.x;
    __shared__ float T[128][129];

    const float* src;
    if (u < 3)       src = embW + (size_t)u * 16384;
    else if (u < 7)  { const float* p[4] = {keyW, qryW, valW, skpW}; src = p[u - 3]; }
    else if (u < 11) { const float* p[4] = {keyW, qryW, valW, skpW}; src = p[u - 7] + 16384; }
    else if (u == 11) src = g1W;
    else if (u == 12) src = g2W;
    else if (u == 13) src = h1W;
    else              src = h2W;

    #pragma unroll
    for (int i = 0; i < 64; ++i) {
        int idx = t + 256 * i;
        T[idx >> 7][idx & 127] = src[idx];
    }
    __syncthreads();

    unsigned short* dH = Wt + (size_t)u * 32768;
    unsigned short* dL = dH + 16384;
    const int m = t >> 1, kbase = (t & 1) * 64;
    for (int j = 0; j < 64; ++j) {
        int k = kbase + j;
        float a = T[k][m];
        unsigned int b = __float_as_uint(a);
        unsigned int h = b & 0xFFFF0000u;
        float r = a - __uint_as_float(h);
        dH[m * 128 + k] = (unsigned short)(h >> 16);
        dL[m * 128 + k] = (unsigned short)(__float_as_uint(r) >> 16);
    }

    if (u == 0) {
        for (int x = t; x < 1024; x += 256) {
            int L = x >> 9, c = x & 511;
            const float* bp = (c < 128) ? keyb : (c < 256) ? qryb : (c < 384) ? valb : skpb;
            biasCat[x] = bp[L * 128 + (c & 127)];
        }
    }
}

// ---------------- CSR build ----------------
__global__ void hist_kernel(const int* __restrict__ dstA, int* __restrict__ hist, int E)
{
    for (int e = blockIdx.x * blockDim.x + threadIdx.x; e < E;
         e += gridDim.x * blockDim.x)
        atomicAdd(&hist[dstA[e]], 1);
}

__global__ __launch_bounds__(256) void scan1_kernel(
    const int* __restrict__ in, int n_in,
    int* __restrict__ out, int* __restrict__ bsum, int n)
{
    __shared__ int wtot[4];
    const int t = threadIdx.x, lane = t & 63, wv = t >> 6;
    const int base = blockIdx.x * 1024 + t * 4;
    int v[4]; int sum = 0;
    #pragma unroll
    for (int j = 0; j < 4; ++j) {
        int idx = base + j;
        v[j] = (idx < n_in) ? in[idx] : 0;
        sum += v[j];
    }
    int incl = sum;
    #pragma unroll
    for (int d = 1; d < 64; d <<= 1) {
        int y = __shfl_up(incl, d, 64);
        if (lane >= d) incl += y;
    }
    if (lane == 63) wtot[wv] = incl;
    __syncthreads();
    int woff = 0;
    for (int w = 0; w < wv; ++w) woff += wtot[w];
    int run = woff + incl - sum;
    #pragma unroll
    for (int j = 0; j < 4; ++j) {
        int idx = base + j;
        if (idx < n) out[idx] = run;
        run += v[j];
    }
    if (t == 0)
        bsum[blockIdx.x] = wtot[0] + wtot[1] + wtot[2] + wtot[3];
}

__global__ void scan2_kernel(int* __restrict__ bsum, int nb)
{
    if (blockIdx.x == 0 && threadIdx.x == 0) {
        int run = 0;
        for (int i = 0; i < nb; ++i) { int t = bsum[i]; bsum[i] = run; run += t; }
    }
}

__global__ __launch_bounds__(256) void scan3_kernel(
    int* __restrict__ out, const int* __restrict__ bsum,
    int* __restrict__ cursor, int n, int n_nodes)
{
    const int base = blockIdx.x * 1024 + threadIdx.x * 4;
    const int add = bsum[blockIdx.x];
    #pragma unroll
    for (int j = 0; j < 4; ++j) {
        int idx = base + j;
        if (idx < n) {
            int vv = out[idx] + add;
            out[idx] = vv;
            if (idx < n_nodes) cursor[idx] = vv;
        }
    }
}

__global__ void scatter_kernel(const int* __restrict__ srcA, const int* __restrict__ dstA,
                               int* __restrict__ cursor, int* __restrict__ perm,
                               int* __restrict__ srcp, int E)
{
    for (int e = blockIdx.x * blockDim.x + threadIdx.x; e < E;
         e += gridDim.x * blockDim.x) {
        int d = dstA[e];
        int pos = atomicAdd(&cursor[d], 1);
        perm[pos] = e;
        srcp[pos] = srcA[e];
    }
}

// ---------------- edge aggregation: round-7 proven (wave per dst, ILP) ----------------
__global__ __launch_bounds__(256) void edge_agg6(
    const int* __restrict__ row_ptr, const int* __restrict__ srcp,
    const float* __restrict__ ea, const int* __restrict__ perm,
    const float* __restrict__ We, const float* __restrict__ be,
    const float* __restrict__ fused, float* __restrict__ X, int N)
{
    const int wv = threadIdx.x >> 6, lane = threadIdx.x & 63;
    const int d = blockIdx.x * 4 + wv;
    if (d >= N) return;
    const int c = lane * 2;

    float2 w[21];
    #pragma unroll
    for (int j = 0; j < 21; ++j)
        w[j] = *(const float2*)(We + j * DD + c);
    const float2 b2 = *(const float2*)(be + c);
    const float2 kd = *(const float2*)(fused + (size_t)d * 512 + c);
    const float2 sk = *(const float2*)(fused + (size_t)d * 512 + 384 + c);

    float ax = 0.f, ay = 0.f;
    const int i0 = row_ptr[d], i1 = row_ptr[d + 1];

    for (int i = i0; i < i1; i += 2) {
        const int iA = i;
        const int iB = (i + 1 < i1) ? i + 1 : i1 - 1;
        const float wgtB = (i + 1 < i1) ? 1.f : 0.f;

        const int sA = srcp[iA], sB = srcp[iB];
        const int pA = perm[iA], pB = perm[iB];

        const float* eA = ea + (size_t)pA * 21;
        const float* eB = ea + (size_t)pB * 21;
        float4 A0 = *(const float4*)(eA);      float4 B0 = *(const float4*)(eB);
        float4 A1 = *(const float4*)(eA + 4);  float4 B1 = *(const float4*)(eB + 4);
        float4 A2 = *(const float4*)(eA + 8);  float4 B2 = *(const float4*)(eB + 8);
        float4 A3 = *(const float4*)(eA + 12); float4 B3 = *(const float4*)(eB + 12);
        float4 A4 = *(const float4*)(eA + 16); float4 B4 = *(const float4*)(eB + 16);
        float A5 = eA[20], B5 = eB[20];

        const float* fpA = fused + (size_t)sA * 512;
        const float* fpB = fused + (size_t)sB * 512;
        float2 qA = *(const float2*)(fpA + 128 + c);
        float2 vA = *(const float2*)(fpA + 256 + c);
        float2 qB = *(const float2*)(fpB + 128 + c);
        float2 vB = *(const float2*)(fpB + 256 + c);

        float aA[21] = {A0.x,A0.y,A0.z,A0.w, A1.x,A1.y,A1.z,A1.w,
                        A2.x,A2.y,A2.z,A2.w, A3.x,A3.y,A3.z,A3.w,
                        A4.x,A4.y,A4.z,A4.w, A5};
        float aB[21] = {B0.x,B0.y,B0.z,B0.w, B1.x,B1.y,B1.z,B1.w,
                        B2.x,B2.y,B2.z,B2.w, B3.x,B3.y,B3.z,B3.w,
                        B4.x,B4.y,B4.z,B4.w, B5};

        float pxA[4] = {0,0,0,0}, pyA[4] = {0,0,0,0};
        float pxB[4] = {0,0,0,0}, pyB[4] = {0,0,0,0};
        #pragma unroll
        for (int j = 0; j < 21; ++j) {
            int s = j & 3;
            pxA[s] = fmaf(aA[j], w[j].x, pxA[s]);
            pyA[s] = fmaf(aA[j], w[j].y, pyA[s]);
            pxB[s] = fmaf(aB[j], w[j].x, pxB[s]);
            pyB[s] = fmaf(aB[j], w[j].y, pyB[s]);
        }
        float exA = (pxA[0] + pxA[1]) + (pxA[2] + pxA[3]) + b2.x;
        float eyA = (pyA[0] + pyA[1]) + (pyA[2] + pyA[3]) + b2.y;
        float exB = (pxB[0] + pxB[1]) + (pxB[2] + pxB[3]) + b2.x;
        float eyB = (pyB[0] + pyB[1]) + (pyB[2] + pyB[3]) + b2.y;

        float zxA = kd.x + qA.x + exA;
        float zyA = kd.y + qA.y + eyA;
        float zxB = kd.x + qB.x + exB;
        float zyB = kd.y + qB.y + eyB;

        float gxA = 1.f / (1.f + __expf(-zxA));
        float gyA = 1.f / (1.f + __expf(-zyA));
        float gxB = wgtB / (1.f + __expf(-zxB));
        float gyB = wgtB / (1.f + __expf(-zyB));

        ax = fmaf(gxA, vA.x, ax);
        ay = fmaf(gyA, vA.y, ay);
        ax = fmaf(gxB, vB.x, ax);
        ay = fmaf(gyB, vB.y, ay);
    }

    X[(size_t)d * DD + c]     = fmaxf(ax + sk.x, 0.f);
    X[(size_t)d * DD + c + 1] = fmaxf(ay + sk.y, 0.f);
}

__global__ void cvec_kernel(const float* __restrict__ gsum, const float* __restrict__ h1W,
                            const float* __restrict__ h1b, float* __restrict__ cvec, float invN)
{
    const int m = threadIdx.x;
    float acc = h1b[m];
    for (int k = 0; k < 128; ++k)
        acc = fmaf(gsum[k] * invN, h1W[(size_t)(128 + k) * DD + m], acc);
    cvec[m] = acc;
}

extern "C" void kernel_launch(void* const* d_in, const int* in_sizes, int n_in,
                              void* d_out, int out_size, void* d_ws, size_t ws_size,
                              hipStream_t stream)
{
    const float* G    = (const float*)d_in[0];
    const int*   ei   = (const int*)  d_in[1];
    const float* ea   = (const float*)d_in[2];
    const float* embW = (const float*)d_in[3];
    const float* embb = (const float*)d_in[4];
    const float* keyW = (const float*)d_in[5];
    const float* keyb = (const float*)d_in[6];
    const float* qryW = (const float*)d_in[7];
    const float* qryb = (const float*)d_in[8];
    const float* valW = (const float*)d_in[9];
    const float* valb = (const float*)d_in[10];
    const float* skpW = (const float*)d_in[11];
    const float* skpb = (const float*)d_in[12];
    const float* edgW = (const float*)d_in[13];
    const float* edgb = (const float*)d_in[14];
    const float* g1W  = (const float*)d_in[15];
    const float* g1b  = (const float*)d_in[16];
    const float* g2W  = (const float*)d_in[17];
    const float* g2b  = (const float*)d_in[18];
    const float* h1W  = (const float*)d_in[19];
    const float* h1b  = (const float*)d_in[20];
    const float* h2W  = (const float*)d_in[21];
    const float* h2b  = (const float*)d_in[22];
    const float* h3W  = (const float*)d_in[23];
    const float* h3b  = (const float*)d_in[24];

    const int N = in_sizes[0] / DD;    // 100000
    const int E = in_sizes[2] / 21;    // 1000000
    const int* srcA = ei;
    const int* dstA = ei + E;

    const size_t S = (size_t)N * DD;
    float* bx     = (float*)d_ws;      // [N][128]
    float* b2     = bx + S;            // [N][128]
    float* bfused = b2 + S;            // [N][512]  (K | Q | V | Sk)
    float* gsum   = bfused + (size_t)N * 512;   // 128
    float* cvec   = gsum + DD;         // 128
    float* biasCat= cvec + DD;         // 1024
    unsigned short* Wt = (unsigned short*)(biasCat + 1024);  // 15*32768 ushorts
    int* hist = (int*)((char*)Wt + (size_t)15 * 32768 * 2);  // N
    int* row  = hist + N;              // N+1
    int* cur  = row + N + 1;           // N
    int* bsum = cur + N;               // 128
    int* perm = bsum + 128;            // E
    int* srcp = perm + E;              // E

    const dim3 g4grid((N + 127) / 128, 4);
    const int fgrid   = (N + 63) / 64;
    const int aggGrid = (N + 3) / 4;
    const int nScan = N + 1;
    const int nb = (nScan + 1023) / 1024;

    // ---- weight prep + CSR build ----
    prep_weights<<<15, 256, 0, stream>>>(embW, keyW, qryW, valW, skpW,
                                         g1W, g2W, h1W, h2W,
                                         keyb, qryb, valb, skpb, Wt, biasCat);
    hipMemsetAsync(hist, 0, (size_t)N * sizeof(int), stream);
    hipMemsetAsync(gsum, 0, DD * sizeof(float), stream);
    hist_kernel<<<1024, 256, 0, stream>>>(dstA, hist, E);
    scan1_kernel<<<nb, 256, 0, stream>>>(hist, N, row, bsum, nScan);
    scan2_kernel<<<1, 64, 0, stream>>>(bsum, nb);
    scan3_kernel<<<nb, 256, 0, stream>>>(row, bsum, cur, nScan, N);
    scatter_kernel<<<1024, 256, 0, stream>>>(srcA, dstA, cur, perm, srcp, E);

    #define UNIT(u) (Wt + (size_t)(u) * 32768)

    // ---- embedding MLP fused: G -> bx ----
    fused_emb3<<<fgrid, 256, 0, stream>>>(G, UNIT(0), embb, bx, N);

    // ---- conv layer 0: x=bx -> fused -> edges -> b2 ----
    gemm_mfma<<<g4grid, 256, 0, stream>>>(bx, UNIT(3), biasCat, bfused, N, 512, 0);
    edge_agg6<<<aggGrid, 256, 0, stream>>>(row, srcp, ea, perm,
                                           edgW + 0, edgb + 0, bfused, b2, N);

    // ---- conv layer 1: x=b2 -> fused -> edges -> bx ----
    gemm_mfma<<<g4grid, 256, 0, stream>>>(b2, UNIT(7), biasCat + 512, bfused, N, 512, 0);
    edge_agg6<<<aggGrid, 256, 0, stream>>>(row, srcp, ea, perm,
                                           edgW + 21*DD, edgb + DD, bfused, bx, N);

    // ---- g1+g2+colsum fused: bx -> b2, gsum ----
    fused_g12<<<fgrid, 256, 0, stream>>>(bx, UNIT(11), g1b, g2b, b2, gsum, N);

    // ---- cvec = h1b + (gmean @ h1W[D:]) ----
    cvec_kernel<<<1, DD, 0, stream>>>(gsum, h1W, h1b, cvec, 1.0f / (float)N);

    // ---- head fused: b2 -> out ----
    fused_head<<<fgrid, 256, 0, stream>>>(b2, UNIT(13), cvec, h2b, h3W, h3b,
                                          (float*)d_out, N);
}